// Round 5
// baseline (465.662 us; speedup 1.0000x reference)
//
#include <hip/hip_runtime.h>

// GraphConv fused pipeline, v7: phase D gather rebuilt on
// __builtin_amdgcn_global_load_lds (DMA direct-to-LDS, per-lane global src,
// zero dest VGPRs) with a per-wave 3-deep ring + counted vmcnt.
// Evidence trail:
//  - v2/v4/v5/v6: main stuck 49.5-52.5 us; VGPR pinned 60-64 in ALL of them.
//    Named 2-deep register pipeline (v6) was still collapsed by the
//    allocator. Register-staged gather MLP is unreachable from HIP source.
//  - global_load_lds sidesteps the RF: outstanding loads bounded by vmcnt
//    (63), not registers. In-flight bytes/CU: 12 waves x 3 KB = 36 KB vs
//    ~4 KB today.
//  - Aggregation via LDS float atomics into aggT: bank = (f*65+d)%32 =
//    (f+d)%32 -> 2-way max (free, m136). dst sort obsolete -> phases A/B/C
//    and the shfl-xor reduce DELETED. Pad edges: src=0, d=64 -> land in
//    aggT's KPAD pad column (never read by phase E).
// LDS: aggT 16640 + xT 16640 + srcL 4096 + dstL 2048 + stg 12288 ~ 50.5 KB
// -> still 3 blocks/CU.
// Constructs deliberately avoided: `#pragma unroll 1` (container-failure
// rounds R11-R13).

#define FEAT 64     // feature dim (F_IN == F_OUT)
#define TNODES 64   // nodes per destination tile
#define TCAP 2048   // per-tile bucket capacity (mean 1024, ~32 sigma margin)
#define KPAD 65     // k-major LDS row stride (floats); col 64 = pad dump
#define CSTR 16     // tile counter stride: one counter per 64 B line
#define TMAX 1024   // max tiles in binner LDS tables
#define GBIN 256    // binner grid
#define RING 3      // per-wave DMA ring depth (3 KB staging per wave)

// prep: WT[k][o] = W[o][k] for both weight matrices + zero tile counters
__global__ __launch_bounds__(256) void gcv2_prep(
    const float* __restrict__ W_rel, const float* __restrict__ W_root,
    float* __restrict__ WTrel, float* __restrict__ WTroot,
    int* __restrict__ tcnt, int n_cnt) {
  const int idx = blockIdx.x * 256 + threadIdx.x;
  if (idx < FEAT * FEAT) {
    const int o = idx >> 6, k = idx & 63;
    WTrel[k * FEAT + o] = W_rel[idx];
    WTroot[k * FEAT + o] = W_root[idx];
  }
  for (int i = idx; i < n_cnt; i += gridDim.x * 256) tcnt[i] = 0;
}

// binner: per-block LDS histogram -> one global atomic per (block,tile)
// region reservation -> dense packed writes (kills partial-line writeback).
// entry = dst<<16 | src  (valid since n_nodes = 50000 < 65536)
__global__ __launch_bounds__(256) void gcv2_bin(
    const int* __restrict__ eidx, int* __restrict__ tcnt,
    unsigned* __restrict__ tbuf, int n_edges, int n_tiles) {
  __shared__ int bh[TMAX];
  __shared__ int bbase[TMAX];

  const int t = threadIdx.x;
  for (int i = t; i < n_tiles; i += 256) bh[i] = 0;
  __syncthreads();

  const int per = (n_edges + gridDim.x - 1) / gridDim.x;
  const int e0 = blockIdx.x * per;
  const int e1 = min(e0 + per, n_edges);

  for (int e = e0 + t; e < e1; e += 256)
    atomicAdd(&bh[eidx[n_edges + e] >> 6], 1);
  __syncthreads();

  for (int i = t; i < n_tiles; i += 256) {
    const int c = bh[i];
    bbase[i] = (c > 0) ? atomicAdd(&tcnt[i * CSTR], c) : 0;
    bh[i] = 0;
  }
  __syncthreads();

  for (int e = e0 + t; e < e1; e += 256) {
    const int s = eidx[e];
    const int d = eidx[n_edges + e];
    const int tl = d >> 6;
    const int p = bbase[tl] + atomicAdd(&bh[tl], 1);
    if (p < TCAP)
      tbuf[(size_t)tl * TCAP + p] = ((unsigned)d << 16) | (unsigned)s;
  }
}

// DMA 16 B/lane global->LDS. LDS dest is wave-uniform base + lane*16;
// global src is per-lane (the gather). No dest VGPRs, counted by vmcnt.
__device__ __forceinline__ void load_lds16(const float* g, float* l) {
  __builtin_amdgcn_global_load_lds(
      (const __attribute__((address_space(1))) unsigned*)g,
      (__attribute__((address_space(3))) unsigned*)l, 16, 0, 0);
}

// fused per-tile: entry staging -> per-wave DMA-ring gather with LDS-atomic
// aggregation -> register-blocked GEMM + bias + ReLU (phase E unchanged).
__global__ __launch_bounds__(256, 3) void gcv2_main(
    const float* __restrict__ x,
    const float* __restrict__ WTrel,   // [FEAT][FEAT] k-major
    const float* __restrict__ b_rel,   // [FEAT]
    const float* __restrict__ WTroot,  // [FEAT][FEAT] k-major
    const int* __restrict__ tcnt,
    const unsigned* __restrict__ tbuf,
    float* __restrict__ out, int n_nodes) {
  __shared__ float aggT[FEAT * KPAD];        // k-major: aggT[k*KPAD + r]
  __shared__ float xT[FEAT * KPAD];          // k-major self tile
  __shared__ unsigned short srcL[TCAP];      // edge srcs (unsorted)
  __shared__ unsigned char dstL[TCAP];       // edge local dsts (64 = pad)
  __shared__ float stg[4][RING][256];        // per-wave DMA staging ring

  const int t = threadIdx.x;
  const int lane = t & 63;
  const int w = t >> 6;
  const int tile = blockIdx.x;
  const int node0 = tile * TNODES;
  const int cnt = min(tcnt[tile * CSTR], TCAP);
  const unsigned* lst = tbuf + (size_t)tile * TCAP;
  const int cnt_pad = (cnt + 15) & ~15;

  // phase 0: zero aggT, stage entries (split src/dst, pad), stage xT
  for (int i = t; i < FEAT * KPAD; i += 256) aggT[i] = 0.f;
  for (int i = t; i < cnt_pad; i += 256) {
    const unsigned e = (i < cnt) ? lst[i] : 0u;
    srcL[i] = (unsigned short)(e & 0xFFFFu);
    dstL[i] = (i < cnt) ? (unsigned char)((e >> 16) & 63) : (unsigned char)64;
  }
  {
    const int c4 = t & 15;
    const int rr = t >> 4;
#pragma unroll
    for (int p = 0; p < 4; ++p) {
      const int r = p * 16 + rr;
      const int gi = node0 + r;
      float4 v = make_float4(0.f, 0.f, 0.f, 0.f);
      if (gi < n_nodes) v = *(const float4*)(x + (size_t)gi * FEAT + c4 * 4);
      xT[(c4 * 4 + 0) * KPAD + r] = v.x;
      xT[(c4 * 4 + 1) * KPAD + r] = v.y;
      xT[(c4 * 4 + 2) * KPAD + r] = v.z;
      xT[(c4 * 4 + 3) * KPAD + r] = v.w;
    }
  }
  __syncthreads();  // compiler emits vmcnt(0) lgkmcnt(0) here: clean slate

  // phase D: per-wave 3-deep DMA ring. batch = 4 edges = 1 KB = 1 DMA inst
  // (lane i sources edge i>>4, 16 B chunk i&15). Wave-private staging ->
  // per-wave vmcnt counting is exact; no barriers in the loop.
  {
    const int f = lane;                 // feature owned by this lane
    const int nb = cnt_pad >> 2;        // total batches
    const int nbw = (nb > w) ? ((nb - w + 3) >> 2) : 0;  // this wave's share
    const int aggbase = f * KPAD;
    const int jj = lane >> 4;           // edge slot within batch
    const int ch = lane & 15;           // 16 B chunk within row

#define DMA_ISSUE(Q, S)                                                   \
  {                                                                       \
    const int b_ = w + ((Q) << 2);                                        \
    const unsigned s_ = srcL[(b_ << 2) + jj];                             \
    load_lds16(x + ((size_t)s_ << 6) + (ch << 2), &stg[w][S][0]);         \
  }

#define REDUCE(Q, S)                                                      \
  {                                                                       \
    const int b_ = w + ((Q) << 2);                                        \
    const unsigned dp_ = *(const unsigned*)&dstL[b_ << 2];                \
    const float* sp_ = &stg[w][S][0];                                     \
    const float v0_ = sp_[f];                                             \
    const float v1_ = sp_[64 + f];                                        \
    const float v2_ = sp_[128 + f];                                       \
    const float v3_ = sp_[192 + f];                                       \
    atomicAdd(&aggT[aggbase + (int)(dp_ & 255u)], v0_);                   \
    atomicAdd(&aggT[aggbase + (int)((dp_ >> 8) & 255u)], v1_);            \
    atomicAdd(&aggT[aggbase + (int)((dp_ >> 16) & 255u)], v2_);           \
    atomicAdd(&aggT[aggbase + (int)(dp_ >> 24)], v3_);                    \
  }

    if (nbw > 0) {
      DMA_ISSUE(0, 0);
      if (nbw > 1) DMA_ISSUE(1, 1);
      if (nbw > 2) DMA_ISSUE(2, 2);
      int s = 0;
      for (int q = 0; q < nbw; ++q) {
        if (q + RING < nbw) {
          asm volatile("s_waitcnt vmcnt(2)" ::: "memory");
        } else {
          asm volatile("s_waitcnt vmcnt(0)" ::: "memory");
        }
        __builtin_amdgcn_sched_barrier(0);
        REDUCE(q, s);
        __builtin_amdgcn_sched_barrier(0);
        if (q + RING < nbw) DMA_ISSUE(q + RING, s);
        s = (s == RING - 1) ? 0 : s + 1;
      }
    }
#undef DMA_ISSUE
#undef REDUCE
  }
  __syncthreads();

  // phase E: out[r][o] = relu(b[o] + sum_k aggT[k][r]*WTrel[k][o]
  //                                  + sum_k xT[k][r]*WTroot[k][o])
  const int oq = t & 15, rq = t >> 4;
  const int o0 = oq * 4, r0 = rq * 4;
  const float4 bias = *(const float4*)(b_rel + o0);
  float acc[4][4];
#pragma unroll
  for (int ri = 0; ri < 4; ++ri) {
    acc[ri][0] = bias.x; acc[ri][1] = bias.y;
    acc[ri][2] = bias.z; acc[ri][3] = bias.w;
  }
#pragma unroll 4
  for (int k = 0; k < FEAT; ++k) {
    const float4 wr = *(const float4*)(WTrel + k * FEAT + o0);
    const float4 wo = *(const float4*)(WTroot + k * FEAT + o0);
    const float a0 = aggT[k * KPAD + r0 + 0], a1 = aggT[k * KPAD + r0 + 1];
    const float a2 = aggT[k * KPAD + r0 + 2], a3 = aggT[k * KPAD + r0 + 3];
    const float x0 = xT[k * KPAD + r0 + 0], x1 = xT[k * KPAD + r0 + 1];
    const float x2 = xT[k * KPAD + r0 + 2], x3 = xT[k * KPAD + r0 + 3];
    acc[0][0] += a0 * wr.x + x0 * wo.x; acc[0][1] += a0 * wr.y + x0 * wo.y;
    acc[0][2] += a0 * wr.z + x0 * wo.z; acc[0][3] += a0 * wr.w + x0 * wo.w;
    acc[1][0] += a1 * wr.x + x1 * wo.x; acc[1][1] += a1 * wr.y + x1 * wo.y;
    acc[1][2] += a1 * wr.z + x1 * wo.z; acc[1][3] += a1 * wr.w + x1 * wo.w;
    acc[2][0] += a2 * wr.x + x2 * wo.x; acc[2][1] += a2 * wr.y + x2 * wo.y;
    acc[2][2] += a2 * wr.z + x2 * wo.z; acc[2][3] += a2 * wr.w + x2 * wo.w;
    acc[3][0] += a3 * wr.x + x3 * wo.x; acc[3][1] += a3 * wr.y + x3 * wo.y;
    acc[3][2] += a3 * wr.z + x3 * wo.z; acc[3][3] += a3 * wr.w + x3 * wo.w;
  }
#pragma unroll
  for (int ri = 0; ri < 4; ++ri) {
    const int gi = node0 + r0 + ri;
    if (gi < n_nodes) {
      float4 o4;
      o4.x = fmaxf(acc[ri][0], 0.f); o4.y = fmaxf(acc[ri][1], 0.f);
      o4.z = fmaxf(acc[ri][2], 0.f); o4.w = fmaxf(acc[ri][3], 0.f);
      *(float4*)(out + (size_t)gi * FEAT + o0) = o4;
    }
  }
}

extern "C" void kernel_launch(void* const* d_in, const int* in_sizes, int n_in,
                              void* d_out, int out_size, void* d_ws, size_t ws_size,
                              hipStream_t stream) {
  const float* x      = (const float*)d_in[0];  // [N, 64]
  const float* W_rel  = (const float*)d_in[1];  // [64, 64]
  const float* b_rel  = (const float*)d_in[2];  // [64]
  const float* W_root = (const float*)d_in[3];  // [64, 64]
  const int* eidx     = (const int*)d_in[4];    // [2, E]

  const int n_nodes = in_sizes[0] / FEAT;
  const int n_edges = in_sizes[4] / 2;
  const int n_tiles = (n_nodes + TNODES - 1) / TNODES;  // 782

  int* tcnt      = (int*)d_ws;                                   // [n_tiles*CSTR]
  unsigned* tbuf = (unsigned*)(tcnt + (size_t)n_tiles * CSTR);   // [n_tiles*TCAP]
  float* WTrel   = (float*)(tbuf + (size_t)n_tiles * TCAP);
  float* WTroot  = WTrel + FEAT * FEAT;

  float* out = (float*)d_out;

  const int n_cnt = n_tiles * CSTR;
  const int gPrep = (n_cnt + 255) / 256;
  gcv2_prep<<<gPrep, 256, 0, stream>>>(W_rel, W_root, WTrel, WTroot, tcnt,
                                       n_cnt);

  gcv2_bin<<<GBIN, 256, 0, stream>>>(eidx, tcnt, tbuf, n_edges, n_tiles);

  gcv2_main<<<n_tiles, 256, 0, stream>>>(x, WTrel, b_rel, WTroot, tcnt, tbuf,
                                         out, n_nodes);
}

// Round 6
// 158.451 us; speedup vs baseline: 2.9388x; 2.9388x over previous
//
#include <hip/hip_runtime.h>

// GraphConv fused pipeline, v8: TNODES 64 -> 32. Double the grid (1563
// blocks, ~6.1/CU, ~24 waves/CU), halve LDS (~19.5 KB), keep the v2
// 256-thread per-thread code shape EXACTLY (the only codegen the compiler
// compiles to the known-good 60-VGPR 4-deep gather).
// Evidence trail:
//  - v2/v4/v5/v6: per-wave ILP is compiler-pinned (VGPR 60-64 always);
//    named-reg pipeline and launch-bounds both inert. Lever abandoned.
//  - v7 (global_load_lds ring): 373 us, VALUBusy 4.7% -- waitcnt pass
//    serializes ds_read vs LDS-DMA. Lever abandoned.
//  - v3 raised occupancy via 512-thr blocks and collapsed VGPR to 20.
//    Untried cell: occupancy via MORE BLOCKS at unchanged block structure.
// Binner: GBIN 256 -> 128 so tcnt global atomics stay ~200k despite 2x
// tiles (v3's GBIN 512 -> +7us showed atomic count is bin's cost).
// Constructs deliberately avoided: __launch_bounds__ min-waves (inert v5,
// spill R9/R10), `#pragma unroll 1` (container failures R11-R13).

#define FEAT 64     // feature dim (F_IN == F_OUT)
#define TNODES 32   // nodes per destination tile (v8: was 64)
#define TCAP 1024   // per-tile bucket capacity (mean 512, ~22 sigma margin)
#define KPAD 33     // k-major LDS row stride (floats)
#define CSTR 16     // tile counter stride: one counter per 64 B line
#define TMAX 1600   // max tiles in binner LDS tables (n_tiles = 1563)
#define GBIN 128    // binner grid (atomics = 128 * 1563 ~ 200k, as before)

// prep: WT[k][o] = W[o][k] for both weight matrices + zero tile counters
__global__ __launch_bounds__(256) void gcv2_prep(
    const float* __restrict__ W_rel, const float* __restrict__ W_root,
    float* __restrict__ WTrel, float* __restrict__ WTroot,
    int* __restrict__ tcnt, int n_cnt) {
  const int idx = blockIdx.x * 256 + threadIdx.x;
  if (idx < FEAT * FEAT) {
    const int o = idx >> 6, k = idx & 63;
    WTrel[k * FEAT + o] = W_rel[idx];
    WTroot[k * FEAT + o] = W_root[idx];
  }
  for (int i = idx; i < n_cnt; i += gridDim.x * 256) tcnt[i] = 0;
}

// binner: per-block LDS histogram -> one global atomic per (block,tile)
// region reservation -> dense packed writes (kills partial-line writeback).
// entry = dst<<16 | src  (valid since n_nodes = 50000 < 65536)
__global__ __launch_bounds__(256) void gcv2_bin(
    const int* __restrict__ eidx, int* __restrict__ tcnt,
    unsigned* __restrict__ tbuf, int n_edges, int n_tiles) {
  __shared__ int bh[TMAX];
  __shared__ int bbase[TMAX];

  const int t = threadIdx.x;
  for (int i = t; i < n_tiles; i += 256) bh[i] = 0;
  __syncthreads();

  const int per = (n_edges + gridDim.x - 1) / gridDim.x;
  const int e0 = blockIdx.x * per;
  const int e1 = min(e0 + per, n_edges);

  for (int e = e0 + t; e < e1; e += 256)
    atomicAdd(&bh[eidx[n_edges + e] >> 5], 1);
  __syncthreads();

  for (int i = t; i < n_tiles; i += 256) {
    const int c = bh[i];
    bbase[i] = (c > 0) ? atomicAdd(&tcnt[i * CSTR], c) : 0;
    bh[i] = 0;
  }
  __syncthreads();

  for (int e = e0 + t; e < e1; e += 256) {
    const int s = eidx[e];
    const int d = eidx[n_edges + e];
    const int tl = d >> 5;
    const int p = bbase[tl] + atomicAdd(&bh[tl], 1);
    if (p < TCAP)
      tbuf[(size_t)tl * TCAP + p] = ((unsigned)d << 16) | (unsigned)s;
  }
}

// fused per-tile: in-LDS counting sort by local dst -> atomic-free dense
// gather (4-deep float4 MLP + shfl_xor slot-reduce) -> register-blocked
// GEMM + bias + ReLU.  v2 per-thread code shape at TNODES=32.
__global__ __launch_bounds__(256) void gcv2_main(
    const float* __restrict__ x,
    const float* __restrict__ WTrel,   // [FEAT][FEAT] k-major
    const float* __restrict__ b_rel,   // [FEAT]
    const float* __restrict__ WTroot,  // [FEAT][FEAT] k-major
    const int* __restrict__ tcnt,
    const unsigned* __restrict__ tbuf,
    float* __restrict__ out, int n_nodes) {
  __shared__ float aggT[FEAT * KPAD];         // k-major: aggT[k*KPAD + r]
  __shared__ float xT[FEAT * KPAD];           // k-major self tile
  __shared__ unsigned short srcs[TCAP + 64];  // dst-sorted srcs (+pad)
  __shared__ int sh[TNODES];
  __shared__ int soff[TNODES + 1];
  __shared__ int scur[TNODES];

  const int t = threadIdx.x;
  const int lane = t & 63;
  const int w = t >> 6;
  const int tile = blockIdx.x;
  const int node0 = tile * TNODES;
  const int cnt = min(tcnt[tile * CSTR], TCAP);
  const unsigned* lst = tbuf + (size_t)tile * TCAP;

  // phase 0: zero histogram, zero srcs pad, stage xT (k-major)
  if (t < TNODES) sh[t] = 0;
  if (t < 64 && cnt + t < TCAP + 64) srcs[cnt + t] = 0;
  {
    const int c4 = t & 15;
    const int rr = t >> 4;
#pragma unroll
    for (int p = 0; p < 2; ++p) {
      const int r = p * 16 + rr;
      const int gi = node0 + r;
      float4 v = make_float4(0.f, 0.f, 0.f, 0.f);
      if (gi < n_nodes) v = *(const float4*)(x + (size_t)gi * FEAT + c4 * 4);
      xT[(c4 * 4 + 0) * KPAD + r] = v.x;
      xT[(c4 * 4 + 1) * KPAD + r] = v.y;
      xT[(c4 * 4 + 2) * KPAD + r] = v.z;
      xT[(c4 * 4 + 3) * KPAD + r] = v.w;
    }
  }
  __syncthreads();

  // phase A: histogram by local dst (int LDS atomics)
  for (int i = t; i < cnt; i += 256) atomicAdd(&sh[(lst[i] >> 16) & 31], 1);
  __syncthreads();

  // phase B: 32-wide exclusive scan in wave 0
  if (w == 0 && lane < 32) {
    int v = sh[lane];
    int s = v;
#pragma unroll
    for (int d = 1; d < 32; d <<= 1) {
      int u = __shfl_up(s, d, 32);
      if (lane >= d) s += u;
    }
    soff[lane] = s - v;
    scur[lane] = s - v;
    if (lane == 31) soff[32] = s;  // == cnt
  }
  __syncthreads();

  // phase C: counting-sort scatter into srcs[]
  for (int i = t; i < cnt; i += 256) {
    const unsigned e = lst[i];
    const int d = (int)((e >> 16) & 31);
    srcs[atomicAdd(&scur[d], 1)] = (unsigned short)(e & 0xFFFFu);
  }
  __syncthreads();

  // phase D: dense per-node gather; lanes = 4 edge-slots x 16 feature-quads;
  // 8 nodes per wave (32 nodes / 4 waves), v2 4-deep chunk-16 body.
  const int slot = lane >> 4;
  const int fq = lane & 15;
  for (int nn = 0; nn < 8; ++nn) {
    const int d = w * 8 + nn;
    const int jb = soff[d];
    const int je = soff[d + 1];
    float4 acc = make_float4(0.f, 0.f, 0.f, 0.f);
    const int i0 = slot, i1 = 4 + slot, i2 = 8 + slot, i3 = 12 + slot;
    for (int e0 = jb; e0 < je; e0 += 16) {
      const int m = je - e0;
      const int j0 = (i0 < m) ? e0 + i0 : cnt;  // pad slot -> src 0
      const int j1 = (i1 < m) ? e0 + i1 : cnt;
      const int j2 = (i2 < m) ? e0 + i2 : cnt;
      const int j3 = (i3 < m) ? e0 + i3 : cnt;
      const int s0 = (int)srcs[j0];
      const int s1 = (int)srcs[j1];
      const int s2 = (int)srcs[j2];
      const int s3 = (int)srcs[j3];
      const float4 f0 = *(const float4*)(x + (size_t)s0 * FEAT + fq * 4);
      const float4 f1 = *(const float4*)(x + (size_t)s1 * FEAT + fq * 4);
      const float4 f2 = *(const float4*)(x + (size_t)s2 * FEAT + fq * 4);
      const float4 f3 = *(const float4*)(x + (size_t)s3 * FEAT + fq * 4);
      acc.x += (i0 < m ? f0.x : 0.f); acc.y += (i0 < m ? f0.y : 0.f);
      acc.z += (i0 < m ? f0.z : 0.f); acc.w += (i0 < m ? f0.w : 0.f);
      acc.x += (i1 < m ? f1.x : 0.f); acc.y += (i1 < m ? f1.y : 0.f);
      acc.z += (i1 < m ? f1.z : 0.f); acc.w += (i1 < m ? f1.w : 0.f);
      acc.x += (i2 < m ? f2.x : 0.f); acc.y += (i2 < m ? f2.y : 0.f);
      acc.z += (i2 < m ? f2.z : 0.f); acc.w += (i2 < m ? f2.w : 0.f);
      acc.x += (i3 < m ? f3.x : 0.f); acc.y += (i3 < m ? f3.y : 0.f);
      acc.z += (i3 < m ? f3.z : 0.f); acc.w += (i3 < m ? f3.w : 0.f);
    }
    acc.x += __shfl_xor(acc.x, 16, 64); acc.y += __shfl_xor(acc.y, 16, 64);
    acc.z += __shfl_xor(acc.z, 16, 64); acc.w += __shfl_xor(acc.w, 16, 64);
    acc.x += __shfl_xor(acc.x, 32, 64); acc.y += __shfl_xor(acc.y, 32, 64);
    acc.z += __shfl_xor(acc.z, 32, 64); acc.w += __shfl_xor(acc.w, 32, 64);
    if (slot == 0) {
      aggT[(fq * 4 + 0) * KPAD + d] = acc.x;
      aggT[(fq * 4 + 1) * KPAD + d] = acc.y;
      aggT[(fq * 4 + 2) * KPAD + d] = acc.z;
      aggT[(fq * 4 + 3) * KPAD + d] = acc.w;
    }
  }
  __syncthreads();

  // phase E: out[r][o] = relu(b[o] + sum_k aggT[k][r]*WTrel[k][o]
  //                                  + sum_k xT[k][r]*WTroot[k][o])
  // 256 threads: 16 o-quads x 16 r-pairs -> 2x4 acc per thread (32 rows)
  const int oq = t & 15, rq = t >> 4;
  const int o0 = oq * 4, r0 = rq * 2;
  const float4 bias = *(const float4*)(b_rel + o0);
  float acc[2][4];
#pragma unroll
  for (int ri = 0; ri < 2; ++ri) {
    acc[ri][0] = bias.x; acc[ri][1] = bias.y;
    acc[ri][2] = bias.z; acc[ri][3] = bias.w;
  }
#pragma unroll 4
  for (int k = 0; k < FEAT; ++k) {
    const float4 wr = *(const float4*)(WTrel + k * FEAT + o0);
    const float4 wo = *(const float4*)(WTroot + k * FEAT + o0);
    const float a0 = aggT[k * KPAD + r0 + 0], a1 = aggT[k * KPAD + r0 + 1];
    const float x0 = xT[k * KPAD + r0 + 0], x1 = xT[k * KPAD + r0 + 1];
    acc[0][0] += a0 * wr.x + x0 * wo.x; acc[0][1] += a0 * wr.y + x0 * wo.y;
    acc[0][2] += a0 * wr.z + x0 * wo.z; acc[0][3] += a0 * wr.w + x0 * wo.w;
    acc[1][0] += a1 * wr.x + x1 * wo.x; acc[1][1] += a1 * wr.y + x1 * wo.y;
    acc[1][2] += a1 * wr.z + x1 * wo.z; acc[1][3] += a1 * wr.w + x1 * wo.w;
  }
#pragma unroll
  for (int ri = 0; ri < 2; ++ri) {
    const int gi = node0 + r0 + ri;
    if (gi < n_nodes) {
      float4 o4;
      o4.x = fmaxf(acc[ri][0], 0.f); o4.y = fmaxf(acc[ri][1], 0.f);
      o4.z = fmaxf(acc[ri][2], 0.f); o4.w = fmaxf(acc[ri][3], 0.f);
      *(float4*)(out + (size_t)gi * FEAT + o0) = o4;
    }
  }
}

extern "C" void kernel_launch(void* const* d_in, const int* in_sizes, int n_in,
                              void* d_out, int out_size, void* d_ws, size_t ws_size,
                              hipStream_t stream) {
  const float* x      = (const float*)d_in[0];  // [N, 64]
  const float* W_rel  = (const float*)d_in[1];  // [64, 64]
  const float* b_rel  = (const float*)d_in[2];  // [64]
  const float* W_root = (const float*)d_in[3];  // [64, 64]
  const int* eidx     = (const int*)d_in[4];    // [2, E]

  const int n_nodes = in_sizes[0] / FEAT;
  const int n_edges = in_sizes[4] / 2;
  const int n_tiles = (n_nodes + TNODES - 1) / TNODES;  // 1563

  int* tcnt      = (int*)d_ws;                                   // [n_tiles*CSTR]
  unsigned* tbuf = (unsigned*)(tcnt + (size_t)n_tiles * CSTR);   // [n_tiles*TCAP]
  float* WTrel   = (float*)(tbuf + (size_t)n_tiles * TCAP);
  float* WTroot  = WTrel + FEAT * FEAT;

  float* out = (float*)d_out;

  const int n_cnt = n_tiles * CSTR;
  const int gPrep = (n_cnt + 255) / 256;
  gcv2_prep<<<gPrep, 256, 0, stream>>>(W_rel, W_root, WTrel, WTroot, tcnt,
                                       n_cnt);

  gcv2_bin<<<GBIN, 256, 0, stream>>>(eidx, tcnt, tbuf, n_edges, n_tiles);

  gcv2_main<<<n_tiles, 256, 0, stream>>>(x, WTrel, b_rel, WTroot, tcnt, tbuf,
                                         out, n_nodes);
}

// Round 7
// 147.631 us; speedup vs baseline: 3.1542x; 1.0733x over previous
//
#include <hip/hip_runtime.h>

// GraphConv fused pipeline, v9: 512-thread blocks for phases 0-D (8 waves,
// 24 waves/CU), with phase E kept as v2's EXACT 4x4-acc code on t<256 to
// pin the kernel VGPR budget at ~60.
// Evidence trail (the model after 6 rounds):
//  - VGPR tracks phase E acc shape: 4x4 -> 60 (v2/v4/v5), 2x4 -> 20 (v3/v8).
//    Phase D inherits that budget as load depth (~4 at 60, ~2 at 20).
//  - time ~ 1/(outstanding loads/CU); all rounds pinned at 48-55:
//    v2 12wv x 4 = 48 -> 49.5us; v3 22 x 2 -> 65us; v8 25 x 2 -> 61us.
//  - v9 opens the untested cell: 24 waves x depth 4 ~ 96 outstanding.
//  - v7 (global_load_lds ring): 373us, VALUBusy 4.7% -- LDS-DMA serializes
//    against ds_read. Abandoned. v6 named-reg pipeline: collapsed. Abandoned.
// Constructs deliberately avoided: __launch_bounds__ min-waves (inert v5,
// spill R9/R10), `#pragma unroll 1` (container failures R11-R13).

#define FEAT 64     // feature dim (F_IN == F_OUT)
#define TNODES 64   // nodes per destination tile
#define TCAP 2048   // per-tile bucket capacity (mean 1024, ~32 sigma margin)
#define KPAD 65     // k-major LDS row stride (floats)
#define CSTR 16     // tile counter stride: one counter per 64 B line
#define TMAX 1024   // max tiles in binner LDS tables
#define GBIN 256    // binner grid
#define MTHR 512    // main kernel block size (8 waves; phase E uses t<256)

// prep: WT[k][o] = W[o][k] for both weight matrices + zero tile counters
__global__ __launch_bounds__(256) void gcv2_prep(
    const float* __restrict__ W_rel, const float* __restrict__ W_root,
    float* __restrict__ WTrel, float* __restrict__ WTroot,
    int* __restrict__ tcnt, int n_cnt) {
  const int idx = blockIdx.x * 256 + threadIdx.x;
  if (idx < FEAT * FEAT) {
    const int o = idx >> 6, k = idx & 63;
    WTrel[k * FEAT + o] = W_rel[idx];
    WTroot[k * FEAT + o] = W_root[idx];
  }
  for (int i = idx; i < n_cnt; i += gridDim.x * 256) tcnt[i] = 0;
}

// binner: per-block LDS histogram -> one global atomic per (block,tile)
// region reservation -> dense packed writes (kills partial-line writeback).
// entry = dst<<16 | src  (valid since n_nodes = 50000 < 65536)
__global__ __launch_bounds__(256) void gcv2_bin(
    const int* __restrict__ eidx, int* __restrict__ tcnt,
    unsigned* __restrict__ tbuf, int n_edges, int n_tiles) {
  __shared__ int bh[TMAX];
  __shared__ int bbase[TMAX];

  const int t = threadIdx.x;
  for (int i = t; i < n_tiles; i += 256) bh[i] = 0;
  __syncthreads();

  const int per = (n_edges + gridDim.x - 1) / gridDim.x;
  const int e0 = blockIdx.x * per;
  const int e1 = min(e0 + per, n_edges);

  for (int e = e0 + t; e < e1; e += 256)
    atomicAdd(&bh[eidx[n_edges + e] >> 6], 1);
  __syncthreads();

  for (int i = t; i < n_tiles; i += 256) {
    const int c = bh[i];
    bbase[i] = (c > 0) ? atomicAdd(&tcnt[i * CSTR], c) : 0;
    bh[i] = 0;
  }
  __syncthreads();

  for (int e = e0 + t; e < e1; e += 256) {
    const int s = eidx[e];
    const int d = eidx[n_edges + e];
    const int tl = d >> 6;
    const int p = bbase[tl] + atomicAdd(&bh[tl], 1);
    if (p < TCAP)
      tbuf[(size_t)tl * TCAP + p] = ((unsigned)d << 16) | (unsigned)s;
  }
}

// fused per-tile: in-LDS counting sort by local dst -> atomic-free dense
// gather (4-deep float4 MLP + shfl_xor slot-reduce, 8 waves x 8 nodes) ->
// register-blocked GEMM + bias + ReLU on t<256 (v2-exact 4x4 shape).
__global__ __launch_bounds__(MTHR) void gcv2_main(
    const float* __restrict__ x,
    const float* __restrict__ WTrel,   // [FEAT][FEAT] k-major
    const float* __restrict__ b_rel,   // [FEAT]
    const float* __restrict__ WTroot,  // [FEAT][FEAT] k-major
    const int* __restrict__ tcnt,
    const unsigned* __restrict__ tbuf,
    float* __restrict__ out, int n_nodes) {
  __shared__ float aggT[FEAT * KPAD];         // k-major: aggT[k*KPAD + r]
  __shared__ float xT[FEAT * KPAD];           // k-major self tile
  __shared__ unsigned short srcs[TCAP + 64];  // dst-sorted srcs (+pad)
  __shared__ int sh[TNODES];
  __shared__ int soff[TNODES + 1];
  __shared__ int scur[TNODES];

  const int t = threadIdx.x;
  const int lane = t & 63;
  const int w = t >> 6;  // 0..7
  const int tile = blockIdx.x;
  const int node0 = tile * TNODES;
  const int cnt = min(tcnt[tile * CSTR], TCAP);
  const unsigned* lst = tbuf + (size_t)tile * TCAP;

  // phase 0: zero histogram, zero srcs pad, stage xT (k-major)
  if (t < TNODES) sh[t] = 0;
  if (t < 64 && cnt + t < TCAP + 64) srcs[cnt + t] = 0;
  {
    const int c4 = t & 15;
    const int rr = t >> 4;  // 0..31
#pragma unroll
    for (int p = 0; p < 2; ++p) {
      const int r = p * 32 + rr;
      const int gi = node0 + r;
      float4 v = make_float4(0.f, 0.f, 0.f, 0.f);
      if (gi < n_nodes) v = *(const float4*)(x + (size_t)gi * FEAT + c4 * 4);
      xT[(c4 * 4 + 0) * KPAD + r] = v.x;
      xT[(c4 * 4 + 1) * KPAD + r] = v.y;
      xT[(c4 * 4 + 2) * KPAD + r] = v.z;
      xT[(c4 * 4 + 3) * KPAD + r] = v.w;
    }
  }
  __syncthreads();

  // phase A: histogram by local dst (int LDS atomics)
  for (int i = t; i < cnt; i += MTHR) atomicAdd(&sh[(lst[i] >> 16) & 63], 1);
  __syncthreads();

  // phase B: 64-wide exclusive scan in wave 0
  if (w == 0) {
    int v = sh[lane];
    int s = v;
#pragma unroll
    for (int d = 1; d < 64; d <<= 1) {
      int u = __shfl_up(s, d, 64);
      if (lane >= d) s += u;
    }
    soff[lane] = s - v;
    scur[lane] = s - v;
    if (lane == 63) soff[64] = s;  // == cnt
  }
  __syncthreads();

  // phase C: counting-sort scatter into srcs[]
  for (int i = t; i < cnt; i += MTHR) {
    const unsigned e = lst[i];
    const int d = (int)((e >> 16) & 63);
    srcs[atomicAdd(&scur[d], 1)] = (unsigned short)(e & 0xFFFFu);
  }
  __syncthreads();

  // phase D: dense per-node gather; lanes = 4 edge-slots x 16 feature-quads;
  // 8 waves x 8 nodes each, v2-exact 4-deep chunk-16 body.
  const int slot = lane >> 4;
  const int fq = lane & 15;
  for (int nn = 0; nn < 8; ++nn) {
    const int d = w * 8 + nn;
    const int jb = soff[d];
    const int je = soff[d + 1];
    float4 acc = make_float4(0.f, 0.f, 0.f, 0.f);
    const int i0 = slot, i1 = 4 + slot, i2 = 8 + slot, i3 = 12 + slot;
    for (int e0 = jb; e0 < je; e0 += 16) {
      const int m = je - e0;
      const int j0 = (i0 < m) ? e0 + i0 : cnt;  // pad slot -> src 0
      const int j1 = (i1 < m) ? e0 + i1 : cnt;
      const int j2 = (i2 < m) ? e0 + i2 : cnt;
      const int j3 = (i3 < m) ? e0 + i3 : cnt;
      const int s0 = (int)srcs[j0];
      const int s1 = (int)srcs[j1];
      const int s2 = (int)srcs[j2];
      const int s3 = (int)srcs[j3];
      const float4 f0 = *(const float4*)(x + (size_t)s0 * FEAT + fq * 4);
      const float4 f1 = *(const float4*)(x + (size_t)s1 * FEAT + fq * 4);
      const float4 f2 = *(const float4*)(x + (size_t)s2 * FEAT + fq * 4);
      const float4 f3 = *(const float4*)(x + (size_t)s3 * FEAT + fq * 4);
      acc.x += (i0 < m ? f0.x : 0.f); acc.y += (i0 < m ? f0.y : 0.f);
      acc.z += (i0 < m ? f0.z : 0.f); acc.w += (i0 < m ? f0.w : 0.f);
      acc.x += (i1 < m ? f1.x : 0.f); acc.y += (i1 < m ? f1.y : 0.f);
      acc.z += (i1 < m ? f1.z : 0.f); acc.w += (i1 < m ? f1.w : 0.f);
      acc.x += (i2 < m ? f2.x : 0.f); acc.y += (i2 < m ? f2.y : 0.f);
      acc.z += (i2 < m ? f2.z : 0.f); acc.w += (i2 < m ? f2.w : 0.f);
      acc.x += (i3 < m ? f3.x : 0.f); acc.y += (i3 < m ? f3.y : 0.f);
      acc.z += (i3 < m ? f3.z : 0.f); acc.w += (i3 < m ? f3.w : 0.f);
    }
    acc.x += __shfl_xor(acc.x, 16, 64); acc.y += __shfl_xor(acc.y, 16, 64);
    acc.z += __shfl_xor(acc.z, 16, 64); acc.w += __shfl_xor(acc.w, 16, 64);
    acc.x += __shfl_xor(acc.x, 32, 64); acc.y += __shfl_xor(acc.y, 32, 64);
    acc.z += __shfl_xor(acc.z, 32, 64); acc.w += __shfl_xor(acc.w, 32, 64);
    if (slot == 0) {
      aggT[(fq * 4 + 0) * KPAD + d] = acc.x;
      aggT[(fq * 4 + 1) * KPAD + d] = acc.y;
      aggT[(fq * 4 + 2) * KPAD + d] = acc.z;
      aggT[(fq * 4 + 3) * KPAD + d] = acc.w;
    }
  }
  __syncthreads();

  // phase E (t<256 only, v2-exact 4x4 shape -> pins VGPR budget ~60):
  // out[r][o] = relu(b[o] + sum_k aggT[k][r]*WTrel[k][o]
  //                        + sum_k xT[k][r]*WTroot[k][o])
  if (t < 256) {
    const int oq = t & 15, rq = t >> 4;
    const int o0 = oq * 4, r0 = rq * 4;
    const float4 bias = *(const float4*)(b_rel + o0);
    float acc[4][4];
#pragma unroll
    for (int ri = 0; ri < 4; ++ri) {
      acc[ri][0] = bias.x; acc[ri][1] = bias.y;
      acc[ri][2] = bias.z; acc[ri][3] = bias.w;
    }
#pragma unroll 4
    for (int k = 0; k < FEAT; ++k) {
      const float4 wr = *(const float4*)(WTrel + k * FEAT + o0);
      const float4 wo = *(const float4*)(WTroot + k * FEAT + o0);
      const float a0 = aggT[k * KPAD + r0 + 0], a1 = aggT[k * KPAD + r0 + 1];
      const float a2 = aggT[k * KPAD + r0 + 2], a3 = aggT[k * KPAD + r0 + 3];
      const float x0 = xT[k * KPAD + r0 + 0], x1 = xT[k * KPAD + r0 + 1];
      const float x2 = xT[k * KPAD + r0 + 2], x3 = xT[k * KPAD + r0 + 3];
      acc[0][0] += a0 * wr.x + x0 * wo.x; acc[0][1] += a0 * wr.y + x0 * wo.y;
      acc[0][2] += a0 * wr.z + x0 * wo.z; acc[0][3] += a0 * wr.w + x0 * wo.w;
      acc[1][0] += a1 * wr.x + x1 * wo.x; acc[1][1] += a1 * wr.y + x1 * wo.y;
      acc[1][2] += a1 * wr.z + x1 * wo.z; acc[1][3] += a1 * wr.w + x1 * wo.w;
      acc[2][0] += a2 * wr.x + x2 * wo.x; acc[2][1] += a2 * wr.y + x2 * wo.y;
      acc[2][2] += a2 * wr.z + x2 * wo.z; acc[2][3] += a2 * wr.w + x2 * wo.w;
      acc[3][0] += a3 * wr.x + x3 * wo.x; acc[3][1] += a3 * wr.y + x3 * wo.y;
      acc[3][2] += a3 * wr.z + x3 * wo.z; acc[3][3] += a3 * wr.w + x3 * wo.w;
    }
#pragma unroll
    for (int ri = 0; ri < 4; ++ri) {
      const int gi = node0 + r0 + ri;
      if (gi < n_nodes) {
        float4 o4;
        o4.x = fmaxf(acc[ri][0], 0.f); o4.y = fmaxf(acc[ri][1], 0.f);
        o4.z = fmaxf(acc[ri][2], 0.f); o4.w = fmaxf(acc[ri][3], 0.f);
        *(float4*)(out + (size_t)gi * FEAT + o0) = o4;
      }
    }
  }
}

extern "C" void kernel_launch(void* const* d_in, const int* in_sizes, int n_in,
                              void* d_out, int out_size, void* d_ws, size_t ws_size,
                              hipStream_t stream) {
  const float* x      = (const float*)d_in[0];  // [N, 64]
  const float* W_rel  = (const float*)d_in[1];  // [64, 64]
  const float* b_rel  = (const float*)d_in[2];  // [64]
  const float* W_root = (const float*)d_in[3];  // [64, 64]
  const int* eidx     = (const int*)d_in[4];    // [2, E]

  const int n_nodes = in_sizes[0] / FEAT;
  const int n_edges = in_sizes[4] / 2;
  const int n_tiles = (n_nodes + TNODES - 1) / TNODES;  // 782

  int* tcnt      = (int*)d_ws;                                   // [n_tiles*CSTR]
  unsigned* tbuf = (unsigned*)(tcnt + (size_t)n_tiles * CSTR);   // [n_tiles*TCAP]
  float* WTrel   = (float*)(tbuf + (size_t)n_tiles * TCAP);
  float* WTroot  = WTrel + FEAT * FEAT;

  float* out = (float*)d_out;

  const int n_cnt = n_tiles * CSTR;
  const int gPrep = (n_cnt + 255) / 256;
  gcv2_prep<<<gPrep, 256, 0, stream>>>(W_rel, W_root, WTrel, WTroot, tcnt,
                                       n_cnt);

  gcv2_bin<<<GBIN, 256, 0, stream>>>(eidx, tcnt, tbuf, n_edges, n_tiles);

  gcv2_main<<<n_tiles, MTHR, 0, stream>>>(x, WTrel, b_rel, WTroot, tcnt, tbuf,
                                          out, n_nodes);
}

// Round 8
// 147.325 us; speedup vs baseline: 3.1608x; 1.0021x over previous
//
#include <hip/hip_runtime.h>

// GraphConv fused pipeline, v10: v6's named 2-deep register pipeline +
// sched_barrier(0) fences pinning issue-before-consume.
// Diagnosis across 9 rounds:
//  - time ~ constant 49-65us whenever outstanding loads/CU ~ 50:
//    {12wv x 4deep}=49, {22x2}=65, {25x2}=61, {24x2}=56. Depth >4 never ran.
//  - depth collapse mechanism: LLVM MachineScheduler sinks independent
//    VMEM loads below intervening VALU to minimize pressure. v5 proved the
//    VGPR cap is not the blocker (cap 168 -> still chose 60). v6's named
//    registers lacked fences, so the scheduler legally re-serialized.
//  - fix (untried cell): sched_barrier(0) between ISSUE and CONSUME blocks.
//    Waitcnt pass then emits counted vmcnt(8): 16 loads/wave in flight.
//  - v7 (LDS-DMA ring): dead end, 373us. Register path only.
// Non-main time: 91-100us across GBIN 128/256/512 and 2x tiles -> no bin
// signal above noise; fixed overhead. Main is the only live lever.
// Constructs avoided: `#pragma unroll 1` (container failures R11-R13).

#define FEAT 64     // feature dim (F_IN == F_OUT)
#define TNODES 64   // nodes per destination tile
#define TCAP 2048   // per-tile bucket capacity (mean 1024, ~32 sigma margin)
#define KPAD 65     // k-major LDS row stride (floats)
#define CSTR 16     // tile counter stride: one counter per 64 B line
#define TMAX 1024   // max tiles in binner LDS tables
#define GBIN 256    // binner grid
#define CCAP 96     // per-wave chunk-list capacity (worst case 16+2048/32=80)

// prep: WT[k][o] = W[o][k] for both weight matrices + zero tile counters
__global__ __launch_bounds__(256) void gcv2_prep(
    const float* __restrict__ W_rel, const float* __restrict__ W_root,
    float* __restrict__ WTrel, float* __restrict__ WTroot,
    int* __restrict__ tcnt, int n_cnt) {
  const int idx = blockIdx.x * 256 + threadIdx.x;
  if (idx < FEAT * FEAT) {
    const int o = idx >> 6, k = idx & 63;
    WTrel[k * FEAT + o] = W_rel[idx];
    WTroot[k * FEAT + o] = W_root[idx];
  }
  for (int i = idx; i < n_cnt; i += gridDim.x * 256) tcnt[i] = 0;
}

// binner: per-block LDS histogram -> one global atomic per (block,tile)
// region reservation -> dense packed writes (kills partial-line writeback).
// entry = dst<<16 | src  (valid since n_nodes = 50000 < 65536)
__global__ __launch_bounds__(256) void gcv2_bin(
    const int* __restrict__ eidx, int* __restrict__ tcnt,
    unsigned* __restrict__ tbuf, int n_edges, int n_tiles) {
  __shared__ int bh[TMAX];
  __shared__ int bbase[TMAX];

  const int t = threadIdx.x;
  for (int i = t; i < n_tiles; i += 256) bh[i] = 0;
  __syncthreads();

  const int per = (n_edges + gridDim.x - 1) / gridDim.x;
  const int e0 = blockIdx.x * per;
  const int e1 = min(e0 + per, n_edges);

  for (int e = e0 + t; e < e1; e += 256)
    atomicAdd(&bh[eidx[n_edges + e] >> 6], 1);
  __syncthreads();

  for (int i = t; i < n_tiles; i += 256) {
    const int c = bh[i];
    bbase[i] = (c > 0) ? atomicAdd(&tcnt[i * CSTR], c) : 0;
    bh[i] = 0;
  }
  __syncthreads();

  for (int e = e0 + t; e < e1; e += 256) {
    const int s = eidx[e];
    const int d = eidx[n_edges + e];
    const int tl = d >> 6;
    const int p = bbase[tl] + atomicAdd(&bh[tl], 1);
    if (p < TCAP)
      tbuf[(size_t)tl * TCAP + p] = ((unsigned)d << 16) | (unsigned)s;
  }
}

// fused per-tile: counting sort by local dst -> chunk-list build ->
// fenced 2-deep pipelined gather -> register-blocked GEMM + bias + ReLU.
__global__ __launch_bounds__(256, 3) void gcv2_main(
    const float* __restrict__ x,
    const float* __restrict__ WTrel,   // [FEAT][FEAT] k-major
    const float* __restrict__ b_rel,   // [FEAT]
    const float* __restrict__ WTroot,  // [FEAT][FEAT] k-major
    const int* __restrict__ tcnt,
    const unsigned* __restrict__ tbuf,
    float* __restrict__ out, int n_nodes) {
  __shared__ float aggT[FEAT * KPAD];         // k-major: aggT[k*KPAD + r]
  __shared__ float xT[FEAT * KPAD];           // k-major self tile
  __shared__ unsigned short srcs[TCAP + 64];  // dst-sorted srcs (+pad)
  __shared__ int sh[TNODES];
  __shared__ int soff[TNODES + 1];
  __shared__ int scur[TNODES];
  __shared__ int cdesc[4 * CCAP];             // per-wave chunk descriptors
  __shared__ int ncK[4];                      // per-wave chunk counts

  const int t = threadIdx.x;
  const int lane = t & 63;
  const int w = t >> 6;
  const int tile = blockIdx.x;
  const int node0 = tile * TNODES;
  const int cnt = min(tcnt[tile * CSTR], TCAP);
  const unsigned* lst = tbuf + (size_t)tile * TCAP;

  // phase 0: zero histogram + aggT, zero srcs pad, stage xT (k-major)
  if (t < TNODES) sh[t] = 0;
  if (t < 64 && cnt + t < TCAP + 64) srcs[cnt + t] = 0;
  for (int i = t; i < FEAT * KPAD; i += 256) aggT[i] = 0.f;
  {
    const int c4 = t & 15;
    const int rr = t >> 4;
#pragma unroll
    for (int p = 0; p < 4; ++p) {
      const int r = p * 16 + rr;
      const int gi = node0 + r;
      float4 v = make_float4(0.f, 0.f, 0.f, 0.f);
      if (gi < n_nodes) v = *(const float4*)(x + (size_t)gi * FEAT + c4 * 4);
      xT[(c4 * 4 + 0) * KPAD + r] = v.x;
      xT[(c4 * 4 + 1) * KPAD + r] = v.y;
      xT[(c4 * 4 + 2) * KPAD + r] = v.z;
      xT[(c4 * 4 + 3) * KPAD + r] = v.w;
    }
  }
  __syncthreads();

  // phase A: histogram by local dst (int LDS atomics)
  for (int i = t; i < cnt; i += 256) atomicAdd(&sh[(lst[i] >> 16) & 63], 1);
  __syncthreads();

  // phase B: 64-wide exclusive scan in wave 0
  if (w == 0) {
    int v = sh[lane];
    int s = v;
#pragma unroll
    for (int d = 1; d < 64; d <<= 1) {
      int u = __shfl_up(s, d, 64);
      if (lane >= d) s += u;
    }
    soff[lane] = s - v;
    scur[lane] = s - v;
    if (lane == 63) soff[64] = s;  // == cnt
  }
  __syncthreads();

  // phase B2: per-wave chunk-list build (lanes 0..15 own 1 node each)
  {
    int myc = 0, jb0 = 0;
    const int nd = w * 16 + (lane & 15);  // local node id 0..63
    if (lane < 16) {
      jb0 = soff[nd];
      const int deg = soff[nd + 1] - jb0;
      myc = (deg + 31) >> 5;  // ceil(deg/32)
    }
    int sc = myc;  // inclusive scan over 16-lane groups
#pragma unroll
    for (int dlt = 1; dlt < 16; dlt <<= 1) {
      const int u = __shfl_up(sc, dlt, 16);
      if ((lane & 15) >= dlt) sc += u;
    }
    const int pos = sc - myc;
    const int tot = __shfl(sc, 15, 64);  // lane 15 holds the wave total
    if (lane == 0) ncK[w] = tot;
    if (lane < 16) {
      for (int c = 0; c < myc; ++c)
        cdesc[w * CCAP + pos + c] = (nd << 16) | (jb0 + c * 32);
    }
  }

  // phase C: counting-sort scatter into srcs[]
  for (int i = t; i < cnt; i += 256) {
    const unsigned e = lst[i];
    const int d = (int)((e >> 16) & 63);
    srcs[atomicAdd(&scur[d], 1)] = (unsigned short)(e & 0xFFFFu);
  }
  __syncthreads();

  // phase D: fenced 2-deep pipelined gather over the wave's chunk list.
  // lanes = 4 edge-slots x 16 feature-quads; 8 float4 loads per chunk;
  // sched_barrier(0) pins issue-before-consume -> counted vmcnt(8),
  // 16 loads/wave in flight (~96 outstanding/CU at 12 waves).
  const int slot = lane >> 4;
  const int fq = lane & 15;
  const int nc = ncK[w];
  const int cbase = w * CCAP;

#define SB() __builtin_amdgcn_sched_barrier(0)

#define GC_ISSUE(DSC, F0, F1, F2, F3, F4, F5, F6, F7)                        \
  {                                                                          \
    const int e0_ = (DSC) & 0xFFFF;                                          \
    const int je_ = soff[((DSC) >> 16) + 1];                                 \
    const int m_ = je_ - e0_;                                                \
    const int j0_ = (slot < m_) ? e0_ + slot : cnt;                          \
    const int j1_ = (4 + slot < m_) ? e0_ + 4 + slot : cnt;                  \
    const int j2_ = (8 + slot < m_) ? e0_ + 8 + slot : cnt;                  \
    const int j3_ = (12 + slot < m_) ? e0_ + 12 + slot : cnt;                \
    const int j4_ = (16 + slot < m_) ? e0_ + 16 + slot : cnt;                \
    const int j5_ = (20 + slot < m_) ? e0_ + 20 + slot : cnt;                \
    const int j6_ = (24 + slot < m_) ? e0_ + 24 + slot : cnt;                \
    const int j7_ = (28 + slot < m_) ? e0_ + 28 + slot : cnt;                \
    const int s0_ = (int)srcs[j0_];                                          \
    const int s1_ = (int)srcs[j1_];                                          \
    const int s2_ = (int)srcs[j2_];                                          \
    const int s3_ = (int)srcs[j3_];                                          \
    const int s4_ = (int)srcs[j4_];                                          \
    const int s5_ = (int)srcs[j5_];                                          \
    const int s6_ = (int)srcs[j6_];                                          \
    const int s7_ = (int)srcs[j7_];                                          \
    F0 = *(const float4*)(x + (size_t)s0_ * FEAT + fq * 4);                  \
    F1 = *(const float4*)(x + (size_t)s1_ * FEAT + fq * 4);                  \
    F2 = *(const float4*)(x + (size_t)s2_ * FEAT + fq * 4);                  \
    F3 = *(const float4*)(x + (size_t)s3_ * FEAT + fq * 4);                  \
    F4 = *(const float4*)(x + (size_t)s4_ * FEAT + fq * 4);                  \
    F5 = *(const float4*)(x + (size_t)s5_ * FEAT + fq * 4);                  \
    F6 = *(const float4*)(x + (size_t)s6_ * FEAT + fq * 4);                  \
    F7 = *(const float4*)(x + (size_t)s7_ * FEAT + fq * 4);                  \
  }

#define GC_CONSUME(DSC, F0, F1, F2, F3, F4, F5, F6, F7)                      \
  {                                                                          \
    const int d_ = (DSC) >> 16;                                              \
    const int e0_ = (DSC) & 0xFFFF;                                          \
    const int m_ = soff[d_ + 1] - e0_;                                       \
    float4 acc = make_float4(0.f, 0.f, 0.f, 0.f);                            \
    acc.x += (slot < m_ ? F0.x : 0.f); acc.y += (slot < m_ ? F0.y : 0.f);    \
    acc.z += (slot < m_ ? F0.z : 0.f); acc.w += (slot < m_ ? F0.w : 0.f);    \
    acc.x += (4 + slot < m_ ? F1.x : 0.f);                                   \
    acc.y += (4 + slot < m_ ? F1.y : 0.f);                                   \
    acc.z += (4 + slot < m_ ? F1.z : 0.f);                                   \
    acc.w += (4 + slot < m_ ? F1.w : 0.f);                                   \
    acc.x += (8 + slot < m_ ? F2.x : 0.f);                                   \
    acc.y += (8 + slot < m_ ? F2.y : 0.f);                                   \
    acc.z += (8 + slot < m_ ? F2.z : 0.f);                                   \
    acc.w += (8 + slot < m_ ? F2.w : 0.f);                                   \
    acc.x += (12 + slot < m_ ? F3.x : 0.f);                                  \
    acc.y += (12 + slot < m_ ? F3.y : 0.f);                                  \
    acc.z += (12 + slot < m_ ? F3.z : 0.f);                                  \
    acc.w += (12 + slot < m_ ? F3.w : 0.f);                                  \
    acc.x += (16 + slot < m_ ? F4.x : 0.f);                                  \
    acc.y += (16 + slot < m_ ? F4.y : 0.f);                                  \
    acc.z += (16 + slot < m_ ? F4.z : 0.f);                                  \
    acc.w += (16 + slot < m_ ? F4.w : 0.f);                                  \
    acc.x += (20 + slot < m_ ? F5.x : 0.f);                                  \
    acc.y += (20 + slot < m_ ? F5.y : 0.f);                                  \
    acc.z += (20 + slot < m_ ? F5.z : 0.f);                                  \
    acc.w += (20 + slot < m_ ? F5.w : 0.f);                                  \
    acc.x += (24 + slot < m_ ? F6.x : 0.f);                                  \
    acc.y += (24 + slot < m_ ? F6.y : 0.f);                                  \
    acc.z += (24 + slot < m_ ? F6.z : 0.f);                                  \
    acc.w += (24 + slot < m_ ? F6.w : 0.f);                                  \
    acc.x += (28 + slot < m_ ? F7.x : 0.f);                                  \
    acc.y += (28 + slot < m_ ? F7.y : 0.f);                                  \
    acc.z += (28 + slot < m_ ? F7.z : 0.f);                                  \
    acc.w += (28 + slot < m_ ? F7.w : 0.f);                                  \
    acc.x += __shfl_xor(acc.x, 16, 64); acc.y += __shfl_xor(acc.y, 16, 64);  \
    acc.z += __shfl_xor(acc.z, 16, 64); acc.w += __shfl_xor(acc.w, 16, 64);  \
    acc.x += __shfl_xor(acc.x, 32, 64); acc.y += __shfl_xor(acc.y, 32, 64);  \
    acc.z += __shfl_xor(acc.z, 32, 64); acc.w += __shfl_xor(acc.w, 32, 64);  \
    if (slot == 0) {                                                         \
      aggT[(fq * 4 + 0) * KPAD + d_] += acc.x;                               \
      aggT[(fq * 4 + 1) * KPAD + d_] += acc.y;                               \
      aggT[(fq * 4 + 2) * KPAD + d_] += acc.z;                               \
      aggT[(fq * 4 + 3) * KPAD + d_] += acc.w;                               \
    }                                                                        \
  }

  {
    int descA = 0, descB = 0;
    float4 fA0, fA1, fA2, fA3, fA4, fA5, fA6, fA7;
    float4 fB0, fB1, fB2, fB3, fB4, fB5, fB6, fB7;
    if (nc > 0) {
      descA = cdesc[cbase];
      GC_ISSUE(descA, fA0, fA1, fA2, fA3, fA4, fA5, fA6, fA7);
    }
    SB();
    for (int j = 0; j < nc; j += 2) {
      const bool hasB = (j + 1 < nc);
      if (hasB) {
        descB = cdesc[cbase + j + 1];
        GC_ISSUE(descB, fB0, fB1, fB2, fB3, fB4, fB5, fB6, fB7);
      }
      SB();  // B's loads may not sink below A's consume
      GC_CONSUME(descA, fA0, fA1, fA2, fA3, fA4, fA5, fA6, fA7);
      SB();  // A's next loads may not hoist above A's consume (reg reuse)
      if (hasB) {
        if (j + 2 < nc) {
          descA = cdesc[cbase + j + 2];
          GC_ISSUE(descA, fA0, fA1, fA2, fA3, fA4, fA5, fA6, fA7);
        }
        SB();  // A' loads may not sink below B's consume
        GC_CONSUME(descB, fB0, fB1, fB2, fB3, fB4, fB5, fB6, fB7);
        SB();
      }
    }
  }
#undef GC_ISSUE
#undef GC_CONSUME
#undef SB
  __syncthreads();

  // phase E: out[r][o] = relu(b[o] + sum_k aggT[k][r]*WTrel[k][o]
  //                                  + sum_k xT[k][r]*WTroot[k][o])
  const int oq = t & 15, rq = t >> 4;
  const int o0 = oq * 4, r0 = rq * 4;
  const float4 bias = *(const float4*)(b_rel + o0);
  float acc[4][4];
#pragma unroll
  for (int ri = 0; ri < 4; ++ri) {
    acc[ri][0] = bias.x; acc[ri][1] = bias.y;
    acc[ri][2] = bias.z; acc[ri][3] = bias.w;
  }
#pragma unroll 4
  for (int k = 0; k < FEAT; ++k) {
    const float4 wr = *(const float4*)(WTrel + k * FEAT + o0);
    const float4 wo = *(const float4*)(WTroot + k * FEAT + o0);
    const float a0 = aggT[k * KPAD + r0 + 0], a1 = aggT[k * KPAD + r0 + 1];
    const float a2 = aggT[k * KPAD + r0 + 2], a3 = aggT[k * KPAD + r0 + 3];
    const float x0 = xT[k * KPAD + r0 + 0], x1 = xT[k * KPAD + r0 + 1];
    const float x2 = xT[k * KPAD + r0 + 2], x3 = xT[k * KPAD + r0 + 3];
    acc[0][0] += a0 * wr.x + x0 * wo.x; acc[0][1] += a0 * wr.y + x0 * wo.y;
    acc[0][2] += a0 * wr.z + x0 * wo.z; acc[0][3] += a0 * wr.w + x0 * wo.w;
    acc[1][0] += a1 * wr.x + x1 * wo.x; acc[1][1] += a1 * wr.y + x1 * wo.y;
    acc[1][2] += a1 * wr.z + x1 * wo.z; acc[1][3] += a1 * wr.w + x1 * wo.w;
    acc[2][0] += a2 * wr.x + x2 * wo.x; acc[2][1] += a2 * wr.y + x2 * wo.y;
    acc[2][2] += a2 * wr.z + x2 * wo.z; acc[2][3] += a2 * wr.w + x2 * wo.w;
    acc[3][0] += a3 * wr.x + x3 * wo.x; acc[3][1] += a3 * wr.y + x3 * wo.y;
    acc[3][2] += a3 * wr.z + x3 * wo.z; acc[3][3] += a3 * wr.w + x3 * wo.w;
  }
#pragma unroll
  for (int ri = 0; ri < 4; ++ri) {
    const int gi = node0 + r0 + ri;
    if (gi < n_nodes) {
      float4 o4;
      o4.x = fmaxf(acc[ri][0], 0.f); o4.y = fmaxf(acc[ri][1], 0.f);
      o4.z = fmaxf(acc[ri][2], 0.f); o4.w = fmaxf(acc[ri][3], 0.f);
      *(float4*)(out + (size_t)gi * FEAT + o0) = o4;
    }
  }
}

extern "C" void kernel_launch(void* const* d_in, const int* in_sizes, int n_in,
                              void* d_out, int out_size, void* d_ws, size_t ws_size,
                              hipStream_t stream) {
  const float* x      = (const float*)d_in[0];  // [N, 64]
  const float* W_rel  = (const float*)d_in[1];  // [64, 64]
  const float* b_rel  = (const float*)d_in[2];  // [64]
  const float* W_root = (const float*)d_in[3];  // [64, 64]
  const int* eidx     = (const int*)d_in[4];    // [2, E]

  const int n_nodes = in_sizes[0] / FEAT;
  const int n_edges = in_sizes[4] / 2;
  const int n_tiles = (n_nodes + TNODES - 1) / TNODES;  // 782

  int* tcnt      = (int*)d_ws;                                   // [n_tiles*CSTR]
  unsigned* tbuf = (unsigned*)(tcnt + (size_t)n_tiles * CSTR);   // [n_tiles*TCAP]
  float* WTrel   = (float*)(tbuf + (size_t)n_tiles * TCAP);
  float* WTroot  = WTrel + FEAT * FEAT;

  float* out = (float*)d_out;

  const int n_cnt = n_tiles * CSTR;
  const int gPrep = (n_cnt + 255) / 256;
  gcv2_prep<<<gPrep, 256, 0, stream>>>(W_rel, W_root, WTrel, WTroot, tcnt,
                                       n_cnt);

  gcv2_bin<<<GBIN, 256, 0, stream>>>(eidx, tcnt, tbuf, n_edges, n_tiles);

  gcv2_main<<<n_tiles, 256, 0, stream>>>(x, WTrel, b_rel, WTroot, tcnt, tbuf,
                                         out, n_nodes);
}